// Round 6
// baseline (130.852 us; speedup 1.0000x reference)
//
#include <hip/hip_runtime.h>

// Masked SDPA: B=8 H=16 S=1024 D=64, fp32 in, FP32 OUT (reference returns f32;
// rounds 0-5 bit-patterns proved the harness buffer is fp32 — bf16 writes were
// the sole bug; MFMA machinery cross-validated vs scalar probe to 5e-4).
// Flash-style, swapped QK^T (mfma(K,Q)); 4 waves x 32 q-rows; KBLK=64;
// K/V staged f16 in LDS (V transposed), P via per-wave LDS in f16.
// f16 (not bf16) fragments: 2^-11 mantissa -> ~4x accuracy margin.
//
// Mask semantics in fp32 (reference adds -1e9 additively):
//   row q < L:  keys k >= L -> -1e9 -> exp underflow 0 (standard mask)
//   row q >= L: ALL keys get -1e9; |s| < ulp(1e9)/2=32 -> every score rounds
//               to exactly -1e9 -> softmax exactly UNIFORM. Implemented s=0.

#define Sdim 1024
#define Ddim 64
#define PITCH 72   // u16 elems per LDS row (64 + 8 pad)

typedef float f32x4 __attribute__((ext_vector_type(4)));
typedef _Float16 f16x8 __attribute__((ext_vector_type(8)));
typedef unsigned short u16x8 __attribute__((ext_vector_type(8)));
typedef unsigned short u16x4 __attribute__((ext_vector_type(4)));

union FragU { u16x8 u; f16x8 h; };

__device__ __forceinline__ unsigned short f2h(float f) {
  _Float16 h = (_Float16)f;
  return __builtin_bit_cast(unsigned short, h);
}

__global__ __launch_bounds__(256, 2)
void attn_fwd(const float* __restrict__ Q, const float* __restrict__ K,
              const float* __restrict__ V, const int* __restrict__ EL,
              float* __restrict__ Out) {
  __shared__ unsigned short k_lds[64 * PITCH];        // [k][d] f16
  __shared__ unsigned short v_lds[64 * PITCH];        // [d][k] f16 (transposed)
  __shared__ unsigned short p_lds[4][32 * PITCH];     // per-wave [q][k] f16

  const int bid = blockIdx.x;
  const int bh  = bid >> 3;          // 0..127
  const int qt  = bid & 7;
  const int b   = bh >> 4;           // H=16
  const int L   = EL[b];

  const int tid  = threadIdx.x;
  const int w    = tid >> 6;
  const int lane = tid & 63;
  const int r    = lane & 15;
  const int hi   = lane >> 4;

  const size_t base = (size_t)bh * Sdim * Ddim;
  const float* Qb = Q + base;
  const float* Kb = K + base;
  const float* Vb = V + base;

  const int q0blk = qt * 128;
  const int q0w   = q0blk + w * 32;

  // ---- Q fragments in registers, pre-scaled by 1/sqrt(D) * log2(e) ----
  const float SCL = 0.125f * 1.44269504088896340736f;
  f16x8 qf[2][2];   // [qc][kk]: Q[q0w+qc*16+r][kk*32+hi*8+j]
#pragma unroll
  for (int qc = 0; qc < 2; ++qc)
#pragma unroll
    for (int kk = 0; kk < 2; ++kk) {
      const float* p = Qb + (size_t)(q0w + qc * 16 + r) * Ddim + kk * 32 + hi * 8;
      float4 a = *(const float4*)p;
      float4 c = *(const float4*)(p + 4);
      FragU f;
      f.u[0] = f2h(a.x * SCL); f.u[1] = f2h(a.y * SCL);
      f.u[2] = f2h(a.z * SCL); f.u[3] = f2h(a.w * SCL);
      f.u[4] = f2h(c.x * SCL); f.u[5] = f2h(c.y * SCL);
      f.u[6] = f2h(c.z * SCL); f.u[7] = f2h(c.w * SCL);
      qf[qc][kk] = f.h;
    }

  const f32x4 zero4 = {0.f, 0.f, 0.f, 0.f};
  f32x4 oacc[2][4];                   // [qc][dc]: O[qc*16+4hi+reg][dc*16+r]
#pragma unroll
  for (int qc = 0; qc < 2; ++qc)
#pragma unroll
    for (int dc = 0; dc < 4; ++dc) oacc[qc][dc] = zero4;

  float mrun[2] = {-3.0e38f, -3.0e38f};
  float lrun[2] = {0.f, 0.f};

  // all-valid block -> only tiles covering [0,L); otherwise full sweep
  const int ntiles = (q0blk + 128 <= L) ? ((L + 63) >> 6) : (Sdim >> 6);

  for (int kt = 0; kt < ntiles; ++kt) {
    const int k0 = kt * 64;
    __syncthreads();   // previous tile's LDS reads complete

    // ---- stage K tile -> k_lds[k][d] (f16) ----
#pragma unroll
    for (int i = 0; i < 4; ++i) {
      int f = tid + 256 * i;            // float4 index, 1024 total
      int row = f >> 4, c4 = f & 15;
      float4 a = *(const float4*)(Kb + (size_t)(k0 + row) * Ddim + c4 * 4);
      u16x4 o; o[0] = f2h(a.x); o[1] = f2h(a.y); o[2] = f2h(a.z); o[3] = f2h(a.w);
      *(u16x4*)&k_lds[row * PITCH + c4 * 4] = o;
    }
    // ---- stage V tile transposed -> v_lds[d][k] via 4x4 register transpose ----
    {
      int kb = tid >> 4, db = tid & 15;
      const float* vp = Vb + (size_t)(k0 + kb * 4) * Ddim + db * 4;
      float4 a0 = *(const float4*)(vp);
      float4 a1 = *(const float4*)(vp + Ddim);
      float4 a2 = *(const float4*)(vp + 2 * Ddim);
      float4 a3 = *(const float4*)(vp + 3 * Ddim);
      u16x4 o;
      o[0]=f2h(a0.x); o[1]=f2h(a1.x); o[2]=f2h(a2.x); o[3]=f2h(a3.x);
      *(u16x4*)&v_lds[(db * 4 + 0) * PITCH + kb * 4] = o;
      o[0]=f2h(a0.y); o[1]=f2h(a1.y); o[2]=f2h(a2.y); o[3]=f2h(a3.y);
      *(u16x4*)&v_lds[(db * 4 + 1) * PITCH + kb * 4] = o;
      o[0]=f2h(a0.z); o[1]=f2h(a1.z); o[2]=f2h(a2.z); o[3]=f2h(a3.z);
      *(u16x4*)&v_lds[(db * 4 + 2) * PITCH + kb * 4] = o;
      o[0]=f2h(a0.w); o[1]=f2h(a1.w); o[2]=f2h(a2.w); o[3]=f2h(a3.w);
      *(u16x4*)&v_lds[(db * 4 + 3) * PITCH + kb * 4] = o;
    }
    __syncthreads();

    // ---- QK^T (swapped: A=K rows, B=Q^T) ----
    // sacc[qc][kc]: S[q = q0w+qc*16+(lane&15)][k = k0+kc*16+4*hi+reg]
    f32x4 sacc[2][4];
#pragma unroll
    for (int qc = 0; qc < 2; ++qc)
#pragma unroll
      for (int kc = 0; kc < 4; ++kc) sacc[qc][kc] = zero4;

#pragma unroll
    for (int kc = 0; kc < 4; ++kc)
#pragma unroll
      for (int kk = 0; kk < 2; ++kk) {
        FragU kf;
        kf.u = *(const u16x8*)&k_lds[(kc * 16 + r) * PITCH + kk * 32 + hi * 8];
        sacc[0][kc] = __builtin_amdgcn_mfma_f32_16x16x32_f16(kf.h, qf[0][kk], sacc[0][kc], 0, 0, 0);
        sacc[1][kc] = __builtin_amdgcn_mfma_f32_16x16x32_f16(kf.h, qf[1][kk], sacc[1][kc], 0, 0, 0);
      }

    // ---- online softmax per q-chunk ----
#pragma unroll
    for (int qc = 0; qc < 2; ++qc) {
      const int qrow = q0w + qc * 16 + r;
      const bool qv = qrow < L;   // valid row: mask k>=L. invalid row: ALL
                                  // scores -> 0 (fp32 -1e9 absorption => uniform)
      float pm = -3.0e38f;
      float pvv[4][4];
#pragma unroll
      for (int kc = 0; kc < 4; ++kc)
#pragma unroll
        for (int rg = 0; rg < 4; ++rg) {
          int kg = k0 + kc * 16 + 4 * hi + rg;
          float s = sacc[qc][kc][rg];
          s = qv ? ((kg < L) ? s : -3.0e38f) : 0.0f;
          sacc[qc][kc][rg] = s;
          pm = fmaxf(pm, s);
        }
      pm = fmaxf(pm, __shfl_xor(pm, 16, 64));
      pm = fmaxf(pm, __shfl_xor(pm, 32, 64));
      float mnew = fmaxf(mrun[qc], pm);
      float fac = exp2f(mrun[qc] - mnew);
      mrun[qc] = mnew;
      float ls = 0.f;
#pragma unroll
      for (int kc = 0; kc < 4; ++kc)
#pragma unroll
        for (int rg = 0; rg < 4; ++rg) {
          float p = exp2f(sacc[qc][kc][rg] - mnew);
          pvv[kc][rg] = p;
          ls += p;
        }
      ls += __shfl_xor(ls, 16, 64);
      ls += __shfl_xor(ls, 32, 64);
      lrun[qc] = lrun[qc] * fac + ls;

      // rescale O rows (O row index is 4*hi+reg; stats live at lane (row))
#pragma unroll
      for (int rg = 0; rg < 4; ++rg) {
        float fo = __shfl(fac, 4 * hi + rg, 64);
#pragma unroll
        for (int dc = 0; dc < 4; ++dc) oacc[qc][dc][rg] *= fo;
      }
      // write P (f16): regs 0..3 are k-consecutive -> packed 8B write
#pragma unroll
      for (int kc = 0; kc < 4; ++kc) {
        u16x4 o;
        o[0] = f2h(pvv[kc][0]); o[1] = f2h(pvv[kc][1]);
        o[2] = f2h(pvv[kc][2]); o[3] = f2h(pvv[kc][3]);
        *(u16x4*)&p_lds[w][(qc * 16 + r) * PITCH + kc * 16 + 4 * hi] = o;
      }
    }

    // P writes -> P reads are same-wave: drain LDS queue, pin order
    asm volatile("s_waitcnt lgkmcnt(0)" ::: "memory");
    __builtin_amdgcn_sched_barrier(0);

    // ---- PV: A = P[q][k], B = V[k][d] (from transposed v_lds) ----
#pragma unroll
    for (int ks = 0; ks < 2; ++ks) {
      FragU pf0, pf1;
      pf0.u = *(const u16x8*)&p_lds[w][(0  + r) * PITCH + ks * 32 + hi * 8];
      pf1.u = *(const u16x8*)&p_lds[w][(16 + r) * PITCH + ks * 32 + hi * 8];
#pragma unroll
      for (int dc = 0; dc < 4; ++dc) {
        FragU vf;
        vf.u = *(const u16x8*)&v_lds[(dc * 16 + r) * PITCH + ks * 32 + hi * 8];
        oacc[0][dc] = __builtin_amdgcn_mfma_f32_16x16x32_f16(pf0.h, vf.h, oacc[0][dc], 0, 0, 0);
        oacc[1][dc] = __builtin_amdgcn_mfma_f32_16x16x32_f16(pf1.h, vf.h, oacc[1][dc], 0, 0, 0);
      }
    }
  }

  // ---- epilogue: divide by row sum, write FP32 ----
  float* ob = Out + base;
#pragma unroll
  for (int qc = 0; qc < 2; ++qc)
#pragma unroll
    for (int rg = 0; rg < 4; ++rg) {
      float lsq = __shfl(lrun[qc], 4 * hi + rg, 64);
      float inv = 1.0f / lsq;
      int qrow = q0w + qc * 16 + 4 * hi + rg;
#pragma unroll
      for (int dc = 0; dc < 4; ++dc)
        ob[(size_t)qrow * Ddim + dc * 16 + r] = oacc[qc][dc][rg] * inv;
    }
}

extern "C" void kernel_launch(void* const* d_in, const int* in_sizes, int n_in,
                              void* d_out, int out_size, void* d_ws, size_t ws_size,
                              hipStream_t stream) {
  const float* q  = (const float*)d_in[0];
  const float* k  = (const float*)d_in[1];
  const float* v  = (const float*)d_in[2];
  const int*   el = (const int*)d_in[3];
  float* out = (float*)d_out;
  dim3 grid(8 * 16 * (Sdim / 128));   // 1024 blocks
  dim3 block(256);
  hipLaunchKernelGGL(attn_fwd, grid, block, 0, stream, q, k, v, el, out);
}

// Round 8
// 77.071 us; speedup vs baseline: 1.6978x; 1.6978x over previous
//
#include <hip/hip_runtime.h>

// Masked SDPA: B=8 H=16 S=1024 D=64, fp32 in, fp32 out.
// Flash-style, swapped QK^T (mfma(K,Q)); 4 waves x 32 q-rows; KBLK=64.
// Round-8 = round-7 with the cvt_pkrtz return-type fix (__fp16 vector ->
// bit_cast via auto). Optimizations over the passing round-6 kernel:
//  - uniform fast-path: tiles with k0 >= L (and fully-invalid waves) skip
//    K-staging/QK/softmax; P is 0/1 written once (fp32 -1e9 absorption =>
//    invalid rows are exactly uniform softmax)
//  - T14 prefetch: next tile's K/V global loads -> regs during compute
//  - defer-max (THR=8 in log2 domain) + per-lane partial row-sum (reduced
//    once at epilogue): softmax shuffles 8 -> 2 per qc per tile
//  - v_cvt_pkrtz_f16_f32 packed conversions
//  - XCD-chunk block swizzle (all 8 q-tiles of a (b,h) on one XCD's L2)
//  - s_setprio around MFMA clusters

#define Sdim 1024
#define Ddim 64
#define PITCH 72   // u16 per LDS row (64 + 8 pad)

typedef float f32x4 __attribute__((ext_vector_type(4)));
typedef _Float16 f16x8 __attribute__((ext_vector_type(8)));
typedef unsigned short u16x8 __attribute__((ext_vector_type(8)));
typedef unsigned int u32x2 __attribute__((ext_vector_type(2)));

union FragU { u16x8 u; f16x8 h; };

__device__ __forceinline__ unsigned pk2(float a, float b) {
  auto h = __builtin_amdgcn_cvt_pkrtz(a, b);   // __fp16 ext_vector(2)
  return __builtin_bit_cast(unsigned, h);
}

__global__ __launch_bounds__(256, 3)
void attn_fwd(const float* __restrict__ Q, const float* __restrict__ K,
              const float* __restrict__ V, const int* __restrict__ EL,
              float* __restrict__ Out) {
  __shared__ unsigned short k_lds[64 * PITCH];        // [k][d] f16
  __shared__ unsigned short v_lds[64 * PITCH];        // [d][k] f16 (transposed)
  __shared__ unsigned short p_lds[4][32 * PITCH];     // per-wave [q][k] f16

  // XCD-chunk swizzle: XCD x serves bh in [x*16, x*16+16), all 8 q-tiles each
  const int bid0 = blockIdx.x;
  const int bid  = (bid0 & 7) * 128 + (bid0 >> 3);
  const int bh   = bid >> 3;
  const int qt   = bid & 7;
  const int L    = EL[bh >> 4];

  const int tid  = threadIdx.x;
  const int w    = tid >> 6;
  const int lane = tid & 63;
  const int r    = lane & 15;
  const int hi   = lane >> 4;

  const size_t base = (size_t)bh * Sdim * Ddim;
  const float* Qb = Q + base;
  const float* Kb = K + base;
  const float* Vb = V + base;

  const int q0blk = qt * 128;
  const int q0w   = q0blk + w * 32;
  const bool wValid = q0w < L;
  const int kFull   = (q0blk >= L) ? 0 : ((L + 63) >> 6);  // tiles w/ valid keys
  const int kFullW  = wValid ? kFull : 0;                  // per-wave compute mode
  const int ntiles  = (q0blk + 128 <= L) ? kFull : 16;

  const bool qv0 = (q0w + r) < L;
  const bool qv1 = (q0w + 16 + r) < L;

  // ---- Q fragments, pre-scaled by 1/sqrt(D)*log2(e) (only if wave has valid rows)
  const float SCL = 0.125f * 1.44269504088896340736f;
  f16x8 qf[2][2];
  if (wValid) {
#pragma unroll
    for (int qc = 0; qc < 2; ++qc)
#pragma unroll
      for (int kk = 0; kk < 2; ++kk) {
        const float* p = Qb + (size_t)(q0w + qc * 16 + r) * Ddim + kk * 32 + hi * 8;
        float4 a = *(const float4*)p;
        float4 c = *(const float4*)(p + 4);
        union { unsigned u[4]; f16x8 h; } f;
        f.u[0] = pk2(a.x * SCL, a.y * SCL); f.u[1] = pk2(a.z * SCL, a.w * SCL);
        f.u[2] = pk2(c.x * SCL, c.y * SCL); f.u[3] = pk2(c.z * SCL, c.w * SCL);
        qf[qc][kk] = f.h;
      }
  }

  const f32x4 zero4 = {0.f, 0.f, 0.f, 0.f};
  f32x4 oacc[2][4];                 // [qc][dc]: O[qc*16+4hi+rg][dc*16+r]
#pragma unroll
  for (int qc = 0; qc < 2; ++qc)
#pragma unroll
    for (int dc = 0; dc < 4; ++dc) oacc[qc][dc] = zero4;

  float mrun[2]  = {-3.0e38f, -3.0e38f};
  float lpart[2] = {0.f, 0.f};      // per-lane partial row-sum (16 k-slots)

  // staging geometry: K rows 16i+sr col sc*4; V rows 4sr+j col sc*4
  const int sr = tid >> 4, sc = tid & 15;
  const float* pK = Kb + (size_t)sr * Ddim + sc * 4;
  const float* pV = Vb + (size_t)(sr * 4) * Ddim + sc * 4;

  float4 kpre[4], vpre[4];
  auto LOADK = [&](int k0_) {
#pragma unroll
    for (int i = 0; i < 4; ++i)
      kpre[i] = *(const float4*)(pK + (size_t)(k0_ + 16 * i) * Ddim);
  };
  auto LOADV = [&](int k0_) {
#pragma unroll
    for (int j = 0; j < 4; ++j)
      vpre[j] = *(const float4*)(pV + (size_t)(k0_ + j) * Ddim);
  };

  if (kFull > 0) LOADK(0);
  LOADV(0);

  for (int kt = 0; kt < ntiles; ++kt) {
    const int k0 = kt * 64;
    const bool fullB = kt < kFull;    // block needs K this tile
    const bool fullW = kt < kFullW;   // this wave computes QK/softmax
    __syncthreads();                  // prior tile's LDS reads complete

    if (fullB) {
#pragma unroll
      for (int i = 0; i < 4; ++i) {
        u32x2 o;
        o[0] = pk2(kpre[i].x, kpre[i].y); o[1] = pk2(kpre[i].z, kpre[i].w);
        *(u32x2*)&k_lds[(16 * i + sr) * PITCH + sc * 4] = o;
      }
    }
    {
      u32x2 o;
      o[0] = pk2(vpre[0].x, vpre[1].x); o[1] = pk2(vpre[2].x, vpre[3].x);
      *(u32x2*)&v_lds[(sc * 4 + 0) * PITCH + sr * 4] = o;
      o[0] = pk2(vpre[0].y, vpre[1].y); o[1] = pk2(vpre[2].y, vpre[3].y);
      *(u32x2*)&v_lds[(sc * 4 + 1) * PITCH + sr * 4] = o;
      o[0] = pk2(vpre[0].z, vpre[1].z); o[1] = pk2(vpre[2].z, vpre[3].z);
      *(u32x2*)&v_lds[(sc * 4 + 2) * PITCH + sr * 4] = o;
      o[0] = pk2(vpre[0].w, vpre[1].w); o[1] = pk2(vpre[2].w, vpre[3].w);
      *(u32x2*)&v_lds[(sc * 4 + 3) * PITCH + sr * 4] = o;
    }
    __syncthreads();

    // prefetch next tile (hidden under compute below)
    if (kt + 1 < kFull)  LOADK(k0 + 64);
    if (kt + 1 < ntiles) LOADV(k0 + 64);

    if (fullW) {
      // ---- QK^T (swapped: A=K rows, B=Q^T) ----
      f32x4 sacc[2][4];
#pragma unroll
      for (int qc = 0; qc < 2; ++qc)
#pragma unroll
        for (int kc = 0; kc < 4; ++kc) sacc[qc][kc] = zero4;

      __builtin_amdgcn_s_setprio(1);
#pragma unroll
      for (int kc = 0; kc < 4; ++kc)
#pragma unroll
        for (int kk = 0; kk < 2; ++kk) {
          FragU kf;
          kf.u = *(const u16x8*)&k_lds[(kc * 16 + r) * PITCH + kk * 32 + hi * 8];
          sacc[0][kc] = __builtin_amdgcn_mfma_f32_16x16x32_f16(kf.h, qf[0][kk], sacc[0][kc], 0, 0, 0);
          sacc[1][kc] = __builtin_amdgcn_mfma_f32_16x16x32_f16(kf.h, qf[1][kk], sacc[1][kc], 0, 0, 0);
        }
      __builtin_amdgcn_s_setprio(0);

      // ---- online softmax (defer-max, partial-lsum) ----
#pragma unroll
      for (int qc = 0; qc < 2; ++qc) {
        const bool qv = qc ? qv1 : qv0;
        float pm = -3.0e38f;
#pragma unroll
        for (int kc = 0; kc < 4; ++kc)
#pragma unroll
          for (int rg = 0; rg < 4; ++rg) {
            int kg = k0 + kc * 16 + 4 * hi + rg;
            float s = sacc[qc][kc][rg];
            s = qv ? ((kg < L) ? s : -3.0e38f) : 0.0f;
            sacc[qc][kc][rg] = s;
            pm = fmaxf(pm, s);
          }
        pm = fmaxf(pm, __shfl_xor(pm, 16, 64));
        pm = fmaxf(pm, __shfl_xor(pm, 32, 64));
        if (__any(pm > mrun[qc] + 8.0f)) {     // rare after first tile
          float mnew = fmaxf(mrun[qc], pm);
          float fac  = exp2f(mrun[qc] - mnew);
          mrun[qc] = mnew;
          lpart[qc] *= fac;
#pragma unroll
          for (int rg = 0; rg < 4; ++rg) {
            float fo = __shfl(fac, 4 * hi + rg, 64);
#pragma unroll
            for (int dc = 0; dc < 4; ++dc) oacc[qc][dc][rg] *= fo;
          }
        }
        float ls = 0.f;
#pragma unroll
        for (int kc = 0; kc < 4; ++kc) {
#pragma unroll
          for (int rg = 0; rg < 4; ++rg) {
            float p = exp2f(sacc[qc][kc][rg] - mrun[qc]);
            sacc[qc][kc][rg] = p;
            ls += p;
          }
          u32x2 o;
          o[0] = pk2(sacc[qc][kc][0], sacc[qc][kc][1]);
          o[1] = pk2(sacc[qc][kc][2], sacc[qc][kc][3]);
          *(u32x2*)&p_lds[w][(qc * 16 + r) * PITCH + kc * 16 + 4 * hi] = o;
        }
        lpart[qc] += ls;
      }
    } else {
      if (kt == kFullW) {
        // uniform P: valid rows 0 (no contribution), invalid rows 1 (uniform)
        unsigned p0 = pk2(qv0 ? 0.f : 1.f, qv0 ? 0.f : 1.f);
        unsigned p1 = pk2(qv1 ? 0.f : 1.f, qv1 ? 0.f : 1.f);
#pragma unroll
        for (int kc = 0; kc < 4; ++kc) {
          u32x2 o0; o0[0] = p0; o0[1] = p0;
          u32x2 o1; o1[0] = p1; o1[1] = p1;
          *(u32x2*)&p_lds[w][(r) * PITCH + kc * 16 + 4 * hi] = o0;
          *(u32x2*)&p_lds[w][(16 + r) * PITCH + kc * 16 + 4 * hi] = o1;
        }
      }
      lpart[0] += qv0 ? 0.f : 16.f;
      lpart[1] += qv1 ? 0.f : 16.f;
    }

    // P writes -> P reads are same-wave: drain LDS queue, pin order
    asm volatile("s_waitcnt lgkmcnt(0)" ::: "memory");
    __builtin_amdgcn_sched_barrier(0);

    // ---- PV: A = P[q][k], B = V[k][d] (transposed v_lds) ----
    __builtin_amdgcn_s_setprio(1);
#pragma unroll
    for (int ks = 0; ks < 2; ++ks) {
      FragU pf0, pf1;
      pf0.u = *(const u16x8*)&p_lds[w][(0  + r) * PITCH + ks * 32 + hi * 8];
      pf1.u = *(const u16x8*)&p_lds[w][(16 + r) * PITCH + ks * 32 + hi * 8];
#pragma unroll
      for (int dc = 0; dc < 4; ++dc) {
        FragU vf;
        vf.u = *(const u16x8*)&v_lds[(dc * 16 + r) * PITCH + ks * 32 + hi * 8];
        oacc[0][dc] = __builtin_amdgcn_mfma_f32_16x16x32_f16(pf0.h, vf.h, oacc[0][dc], 0, 0, 0);
        oacc[1][dc] = __builtin_amdgcn_mfma_f32_16x16x32_f16(pf1.h, vf.h, oacc[1][dc], 0, 0, 0);
      }
    }
    __builtin_amdgcn_s_setprio(0);
  }

  // ---- epilogue: reduce partial row-sums, divide, write fp32 ----
  float* ob = Out + base;
#pragma unroll
  for (int qc = 0; qc < 2; ++qc) {
    float l = lpart[qc];
    l += __shfl_xor(l, 16, 64);
    l += __shfl_xor(l, 32, 64);
#pragma unroll
    for (int rg = 0; rg < 4; ++rg) {
      float lsq = __shfl(l, 4 * hi + rg, 64);
      float inv = 1.0f / lsq;
      int qrow = q0w + qc * 16 + 4 * hi + rg;
#pragma unroll
      for (int dc = 0; dc < 4; ++dc)
        ob[(size_t)qrow * Ddim + dc * 16 + r] = oacc[qc][dc][rg] * inv;
    }
  }
}

extern "C" void kernel_launch(void* const* d_in, const int* in_sizes, int n_in,
                              void* d_out, int out_size, void* d_ws, size_t ws_size,
                              hipStream_t stream) {
  const float* q  = (const float*)d_in[0];
  const float* k  = (const float*)d_in[1];
  const float* v  = (const float*)d_in[2];
  const int*   el = (const int*)d_in[3];
  float* out = (float*)d_out;
  dim3 grid(8 * 16 * (Sdim / 128));   // 1024 blocks
  dim3 block(256);
  hipLaunchKernelGGL(attn_fwd, grid, block, 0, stream, q, k, v, el, out);
}